// Round 7
// baseline (660.859 us; speedup 1.0000x reference)
//
#include <hip/hip_runtime.h>
#include <hip/hip_bf16.h>
#include <math.h>

#define NNODES 100000
#define EPSV 1e-5f
#define NB 196          // ceil(100000/512) coarse buckets of 512 nodes
#define NBLK 256        // partition blocks (fixed; histA/partB must match ranges)

typedef __attribute__((ext_vector_type(8))) short short8v;   // 8 bf16 = 4 VGPR
typedef __attribute__((ext_vector_type(4))) float f32x4;

__device__ __forceinline__ ushort f2bf(float f) {
  uint u = __float_as_uint(f);
  return (ushort)((u + 0x7fffu + ((u >> 16) & 1u)) >> 16);  // RNE
}
__device__ __forceinline__ float bf2f(ushort h) { return __uint_as_float(((uint)h) << 16); }

// swizzled LDS offset for tiles with 256B rows: XOR 16B-granule index with row&7
__device__ __forceinline__ int lds_off(int row, int byteInRow) {
  return row * 256 + ((((byteInRow >> 4) ^ (row & 7)) << 4) | (byteInRow & 15));
}

// ---------------- graph prep: radix partition, no global atomics ----------------

__global__ __launch_bounds__(256) void histA_k(const int* __restrict__ ei, int E,
                                               int* __restrict__ hmatT) {
  __shared__ int lh[NB];
  for (int i = threadIdx.x; i < NB; i += 256) lh[i] = 0;
  __syncthreads();
  int per = (E + NBLK - 1) / NBLK;
  int s0 = blockIdx.x * per, s1 = min(E, s0 + per);
  for (int e = s0 + threadIdx.x; e < s1; e += 256)
    atomicAdd(&lh[ei[E + e] >> 9], 1);
  __syncthreads();
  for (int i = threadIdx.x; i < NB; i += 256)
    hmatT[i * NBLK + blockIdx.x] = lh[i];
}

__global__ __launch_bounds__(256) void scanM_k(const int* __restrict__ hmatT,
                                               int* __restrict__ hbaseT,
                                               int* __restrict__ boff, int E) {
  __shared__ int sm[256];
  int tid = threadIdx.x;
  int tot = 0;
  if (tid < NB) {
    const int* rowp = &hmatT[tid * NBLK];
#pragma unroll 8
    for (int b = 0; b < NBLK; ++b) tot += rowp[b];
  }
  sm[tid] = tot;
  __syncthreads();
  for (int off = 1; off < 256; off <<= 1) {
    int t = (tid >= off) ? sm[tid - off] : 0;
    __syncthreads();
    sm[tid] += t;
    __syncthreads();
  }
  if (tid < NB) {
    int run = sm[tid] - tot;     // exclusive
    boff[tid] = run;
    const int* rowp = &hmatT[tid * NBLK];
    int* basep = &hbaseT[tid * NBLK];
    for (int b = 0; b < NBLK; ++b) {
      int c = rowp[b];
      basep[b] = run;
      run += c;
    }
  }
  if (tid == 0) boff[NB] = E;
}

// packed word: (dst & 511) << 17 | src   (src < 2^17)
__global__ __launch_bounds__(256) void partB_k(const int* __restrict__ ei, int E,
                                               const int* __restrict__ hbaseT,
                                               uint* __restrict__ ebuf) {
  __shared__ int cur[NB];
  for (int i = threadIdx.x; i < NB; i += 256)
    cur[i] = hbaseT[i * NBLK + blockIdx.x];
  __syncthreads();
  int per = (E + NBLK - 1) / NBLK;
  int s0 = blockIdx.x * per, s1 = min(E, s0 + per);
  for (int e = s0 + threadIdx.x; e < s1; e += 256) {
    int s = ei[e];
    int d = ei[E + e];
    int p = atomicAdd(&cur[d >> 9], 1);
    ebuf[p] = ((uint)(d & 511) << 17) | (uint)s;
  }
}

__global__ __launch_bounds__(256) void histnode_k(const uint* __restrict__ ebuf,
                                                  const int* __restrict__ boff,
                                                  int* __restrict__ deg, int n) {
  __shared__ int h[512];
  int b = blockIdx.x;
  for (int i = threadIdx.x; i < 512; i += 256) h[i] = 0;
  __syncthreads();
  int s0 = boff[b], s1 = boff[b + 1];
  for (int i = s0 + threadIdx.x; i < s1; i += 256)
    atomicAdd(&h[ebuf[i] >> 17], 1);
  __syncthreads();
  int nb0 = b * 512;
  for (int i = threadIdx.x; i < 512; i += 256)
    if (nb0 + i < n) deg[nb0 + i] = h[i];
}

__global__ __launch_bounds__(256) void scanA_k(const int* __restrict__ cnt, int* __restrict__ rowst,
                                               int* __restrict__ chunk, int n) {
  __shared__ int sm[256];
  int i = blockIdx.x * 256 + threadIdx.x;
  int v = (i < n) ? cnt[i] : 0;
  sm[threadIdx.x] = v;
  __syncthreads();
  for (int off = 1; off < 256; off <<= 1) {
    int t = (threadIdx.x >= off) ? sm[threadIdx.x - off] : 0;
    __syncthreads();
    sm[threadIdx.x] += t;
    __syncthreads();
  }
  if (i < n) rowst[i] = sm[threadIdx.x];
  if (threadIdx.x == 255) chunk[blockIdx.x] = sm[255];
}

__global__ __launch_bounds__(512) void scanB_k(int* __restrict__ chunk, int nc) {
  __shared__ int sm[512];
  int v = (threadIdx.x < nc) ? chunk[threadIdx.x] : 0;
  sm[threadIdx.x] = v;
  __syncthreads();
  for (int off = 1; off < 512; off <<= 1) {
    int t = (threadIdx.x >= off) ? sm[threadIdx.x - off] : 0;
    __syncthreads();
    sm[threadIdx.x] += t;
    __syncthreads();
  }
  if (threadIdx.x < nc) chunk[threadIdx.x] = sm[threadIdx.x] - v;
}

__global__ __launch_bounds__(256) void scanC_k(const int* __restrict__ cnt, const int* __restrict__ chunk,
                                               int* __restrict__ rowst, int n) {
  int i = blockIdx.x * 256 + threadIdx.x;
  if (i < n) rowst[i] = chunk[blockIdx.x] + rowst[i] - cnt[i];
}

__global__ __launch_bounds__(256) void dinv_k(const int* __restrict__ deg, float* __restrict__ dinv, int n) {
  int i = blockIdx.x * 256 + threadIdx.x;
  if (i < n) dinv[i] = rsqrtf((float)deg[i] + 1.0f);
}

__global__ __launch_bounds__(256) void fillB_k(const uint* __restrict__ ebuf,
                                               const int* __restrict__ boff,
                                               const int* __restrict__ rowst,
                                               int* __restrict__ csr, int n, int E) {
  __shared__ int rst[512];
  __shared__ int cur[512];
  int b = blockIdx.x;
  int nb0 = b * 512;
  for (int i = threadIdx.x; i < 512; i += 256) {
    int node = nb0 + i;
    rst[i] = (node < n) ? rowst[node] : E;
    cur[i] = 0;
  }
  __syncthreads();
  int s0 = boff[b], s1 = boff[b + 1];
  for (int i = s0 + threadIdx.x; i < s1; i += 256) {
    uint w = ebuf[i];
    int l = w >> 17;
    int p = atomicAdd(&cur[l], 1);
    csr[rst[l] + p] = (int)(w & 0x1FFFFu);
  }
}

// ---------------- MFMA GEMM: y_bf16 = dinv[r] * (z @ W) ----------------
// NREAL=128 writes SLICED layout: ys[cg][node][16cols], cg=0..7 (32B per node per slice).
// NREAL=40 writes flat N x 40.

template <int NREAL, bool BN>
__global__ __launch_bounds__(256) void gemm_mfma_k(const float* __restrict__ in, const float* __restrict__ W,
                                                   const float* __restrict__ scale, const float* __restrict__ shift,
                                                   const float* __restrict__ dinv, ushort* __restrict__ y, int n) {
  constexpr int NT = (NREAL + 15) / 16;  // col tiles: 8 or 3
  __shared__ ushort At[64 * 128];        // swizzled A tile; reused as output tile
  __shared__ ushort Wt[NT * 16 * 128];   // swizzled W^T (col-major: [col][k])
  const int tid = threadIdx.x;
  const int row0 = blockIdx.x * 64;

  if constexpr (NREAL != NT * 16) {
    for (int i = tid; i < (NT * 16 - NREAL) * 128; i += 256) {
      int c = NREAL + (i >> 7), k = i & 127;
      *(ushort*)((char*)Wt + lds_off(c, k * 2)) = 0;
    }
  }
  for (int e = tid * 4; e < 128 * NREAL; e += 1024) {
    float4 w4 = *(const float4*)&W[e];
    int k = e / NREAL, c = e % NREAL;
    const float* wp = (const float*)&w4;
#pragma unroll
    for (int j = 0; j < 4; ++j)
      *(ushort*)((char*)Wt + lds_off(c + j, k * 2)) = f2bf(wp[j]);
  }

#pragma unroll
  for (int it = 0; it < 8; ++it) {
    int f = tid + it * 256;
    int r = f >> 5, c4 = (f & 31) * 4;
    int row = row0 + r;
    float4 v;
    if (row < n) v = *(const float4*)&in[(size_t)row * 128 + c4];
    else v = make_float4(0.f, 0.f, 0.f, 0.f);
    if (BN) {
      float4 sc = *(const float4*)&scale[c4];
      float4 sh = *(const float4*)&shift[c4];
      v.x = fmaxf(fmaf(v.x, sc.x, sh.x), 0.f);
      v.y = fmaxf(fmaf(v.y, sc.y, sh.y), 0.f);
      v.z = fmaxf(fmaf(v.z, sc.z, sh.z), 0.f);
      v.w = fmaxf(fmaf(v.w, sc.w, sh.w), 0.f);
    }
    ushort4 h;
    h.x = f2bf(v.x); h.y = f2bf(v.y); h.z = f2bf(v.z); h.w = f2bf(v.w);
    *(ushort4*)((char*)At + lds_off(r, c4 * 2)) = h;
  }
  __syncthreads();

  const int w = tid >> 6, lane = tid & 63;
  const int lr = lane & 15, g = lane >> 4;

  short8v a[4];
#pragma unroll
  for (int kk = 0; kk < 4; ++kk)
    a[kk] = *(const short8v*)((const char*)At + lds_off(w * 16 + lr, kk * 64 + g * 16));
  float dv[4];
#pragma unroll
  for (int i = 0; i < 4; ++i) {
    int rr = row0 + w * 16 + g * 4 + i;
    dv[i] = (rr < n) ? dinv[rr] : 0.f;
  }
  __syncthreads();  // all waves done reading At -> reuse as output tile

#pragma unroll
  for (int ct = 0; ct < NT; ++ct) {
    f32x4 acc = {0.f, 0.f, 0.f, 0.f};
#pragma unroll
    for (int kk = 0; kk < 4; ++kk) {
      short8v b = *(const short8v*)((const char*)Wt + lds_off(ct * 16 + lr, kk * 64 + g * 16));
      acc = __builtin_amdgcn_mfma_f32_16x16x32_bf16(a[kk], b, acc, 0, 0, 0);
    }
#pragma unroll
    for (int i = 0; i < 4; ++i)
      *(ushort*)((char*)At + lds_off(w * 16 + g * 4 + i, (ct * 16 + lr) * 2)) = f2bf(acc[i] * dv[i]);
  }
  __syncthreads();

  if constexpr (NREAL == 128) {
#pragma unroll
    for (int it = 0; it < 4; ++it) {
      int cid = tid + it * 256;
      int r = cid >> 4, gg = cid & 15;   // gg: 16B chunk = cols [gg*8, gg*8+8)
      int row = row0 + r;
      if (row < n) {
        short8v t = *(const short8v*)((const char*)At + lds_off(r, gg * 16));
        int cg = gg >> 1, h = gg & 1;    // slice, half
        *(short8v*)&y[(size_t)cg * n * 16 + (size_t)row * 16 + h * 8] = t;
      }
    }
  } else {
#pragma unroll
    for (int it = 0; it < 3; ++it) {
      int cid = tid + it * 256;
      if (cid < 640) {
        int r = cid / 10, u = cid - r * 10;
        int row = row0 + r;
        if (row < n) {
          ushort4 t = *(const ushort4*)((const char*)At + lds_off(r, u * 8));
          *(ushort4*)&y[(size_t)row * 40 + u * 4] = t;
        }
      }
    }
  }
}

// ---------------- aggregation, 128-wide: sliced y, XCD-pinned column groups ----------------
// grid = 8 * ceil(n/64); cg = blockIdx&7 -> XCD round-robin. Block: 32 groups x 8 lanes,
// each group does 2 nodes; per edge the group gathers 32B (16 cols) from its slice.

__global__ __launch_bounds__(256) void agg128_k(const uint* __restrict__ ys, const int* __restrict__ csr,
                                                const int* __restrict__ rowst, const int* __restrict__ deg,
                                                const float* __restrict__ dinv, const float* __restrict__ bias,
                                                float* __restrict__ out, int n) {
  const int cg = blockIdx.x & 7;
  const int node0 = (blockIdx.x >> 3) * 64;
  const int grp = threadIdx.x >> 3;      // 0..31
  const int gl = threadIdx.x & 7;        // lane in group
  const uint* slice = ys + (size_t)cg * (size_t)n * 8;   // 8 uints (16 bf16) per node
  const float2 bb = *(const float2*)&bias[cg * 16 + gl * 2];

#pragma unroll
  for (int k = 0; k < 2; ++k) {
    int node = node0 + grp + 32 * k;
    if (node >= n) continue;
    int base = rowst[node];
    int dg = deg[node];
    float a0 = 0.f, a1 = 0.f, b0 = 0.f, b1 = 0.f, c0 = 0.f, c1 = 0.f, d0 = 0.f, d1 = 0.f;
    int t = 0;
    for (; t + 4 <= dg; t += 4) {
      int s0 = csr[base + t], s1 = csr[base + t + 1];
      int s2 = csr[base + t + 2], s3 = csr[base + t + 3];
      uint v0 = slice[(size_t)s0 * 8 + gl];
      uint v1 = slice[(size_t)s1 * 8 + gl];
      uint v2 = slice[(size_t)s2 * 8 + gl];
      uint v3 = slice[(size_t)s3 * 8 + gl];
      a0 += __uint_as_float(v0 << 16); a1 += __uint_as_float(v0 & 0xffff0000u);
      b0 += __uint_as_float(v1 << 16); b1 += __uint_as_float(v1 & 0xffff0000u);
      c0 += __uint_as_float(v2 << 16); c1 += __uint_as_float(v2 & 0xffff0000u);
      d0 += __uint_as_float(v3 << 16); d1 += __uint_as_float(v3 & 0xffff0000u);
    }
    for (; t < dg; ++t) {
      int s = csr[base + t];
      uint v = slice[(size_t)s * 8 + gl];
      a0 += __uint_as_float(v << 16); a1 += __uint_as_float(v & 0xffff0000u);
    }
    uint vs = slice[(size_t)node * 8 + gl];
    a0 += __uint_as_float(vs << 16); a1 += __uint_as_float(vs & 0xffff0000u);
    float s0 = (a0 + b0) + (c0 + d0);
    float s1 = (a1 + b1) + (c1 + d1);
    float dvv = dinv[node];
    float2 o;
    o.x = fmaf(s0, dvv, bb.x);
    o.y = fmaf(s1, dvv, bb.y);
    *(float2*)&out[(size_t)node * 128 + cg * 16 + gl * 2] = o;
  }
}

// ---------------- last layer: aggregation (d=40) + bias + log_softmax ----------------

__global__ __launch_bounds__(256) void agg40_lsm_k(const ushort* __restrict__ y, const int* __restrict__ csr,
                                                   const int* __restrict__ rowst, const int* __restrict__ deg,
                                                   const float* __restrict__ dinv, const float* __restrict__ bias,
                                                   float* __restrict__ out, int n) {
  int wid = (blockIdx.x * 256 + threadIdx.x) >> 6;
  if (wid >= n) return;
  int lane = threadIdx.x & 63;
  int col = lane < 40 ? lane : 39;
  int base = rowst[wid];
  int dg = deg[wid];
  float a = 0.f, b = 0.f, c = 0.f, d = 0.f;
  int t = 0;
  for (; t + 4 <= dg; t += 4) {
    int s0 = csr[base + t], s1 = csr[base + t + 1], s2 = csr[base + t + 2], s3 = csr[base + t + 3];
    a += bf2f(y[(size_t)s0 * 40 + col]);
    b += bf2f(y[(size_t)s1 * 40 + col]);
    c += bf2f(y[(size_t)s2 * 40 + col]);
    d += bf2f(y[(size_t)s3 * 40 + col]);
  }
  for (; t < dg; ++t) {
    int s = csr[base + t];
    a += bf2f(y[(size_t)s * 40 + col]);
  }
  a += bf2f(y[(size_t)wid * 40 + col]);
  float v = fmaf((a + b) + (c + d), dinv[wid], bias[col]);
  bool act = lane < 40;
  float m = act ? v : -INFINITY;
#pragma unroll
  for (int off = 32; off; off >>= 1) m = fmaxf(m, __shfl_xor(m, off));
  float e = act ? expf(v - m) : 0.f;
  float se = e;
#pragma unroll
  for (int off = 32; off; off >>= 1) se += __shfl_xor(se, off);
  if (act) out[(size_t)wid * 40 + lane] = v - m - logf(se);
}

// ---------------- BN stats ----------------

__global__ __launch_bounds__(256) void stats_partial_k(const float* __restrict__ h,
                                                       float* __restrict__ ps, float* __restrict__ pss, int n) {
  int c = threadIdx.x & 127;
  int half = threadIdx.x >> 7;
  int r0 = blockIdx.x * 2 + half;
  float s = 0.f, ss = 0.f;
  for (int r = r0; r < n; r += 512) {
    float v = h[(size_t)r * 128 + c];
    s += v;
    ss = fmaf(v, v, ss);
  }
  __shared__ float sm[256], sm2[256];
  sm[threadIdx.x] = s;
  sm2[threadIdx.x] = ss;
  __syncthreads();
  if (threadIdx.x < 128) {
    ps[blockIdx.x * 128 + c] = sm[c] + sm[c + 128];
    pss[blockIdx.x * 128 + c] = sm2[c] + sm2[c + 128];
  }
}

__global__ __launch_bounds__(128) void stats_final_k(const float* __restrict__ ps, const float* __restrict__ pss,
                                                     const float* __restrict__ g, const float* __restrict__ be,
                                                     float* __restrict__ scale, float* __restrict__ shift, int n) {
  int c = threadIdx.x;
  float s = 0.f, ss = 0.f;
  for (int b = 0; b < 256; ++b) {
    s += ps[b * 128 + c];
    ss += pss[b * 128 + c];
  }
  float mu = s / (float)n;
  float var = ss / (float)n - mu * mu;
  float rs = rsqrtf(var + EPSV);
  float sc = rs * g[c];
  scale[c] = sc;
  shift[c] = fmaf(-mu, sc, be[c]);
}

// ---------------- launch ----------------

extern "C" void kernel_launch(void* const* d_in, const int* in_sizes, int n_in,
                              void* d_out, int out_size, void* d_ws, size_t ws_size,
                              hipStream_t stream) {
  const float* x   = (const float*)d_in[0];
  const int*   ei  = (const int*)d_in[1];
  const float* W1  = (const float*)d_in[2];
  const float* b1  = (const float*)d_in[3];
  const float* W2  = (const float*)d_in[4];
  const float* b2  = (const float*)d_in[5];
  const float* W3  = (const float*)d_in[6];
  const float* b3  = (const float*)d_in[7];
  const float* g1  = (const float*)d_in[8];
  const float* be1 = (const float*)d_in[9];
  const float* g2  = (const float*)d_in[10];
  const float* be2 = (const float*)d_in[11];
  float* outp = (float*)d_out;

  const int N = NNODES;
  const int E = in_sizes[1] / 2;
  const int NC = (N + 255) / 256;  // 391

  char* w = (char*)d_ws;
  auto alloc = [&](size_t bytes) -> void* {
    void* p = (void*)w;
    w += (bytes + 255) & ~(size_t)255;
    return p;
  };
  int*    deg    = (int*)alloc((size_t)N * 4);
  int*    rowst  = (int*)alloc((size_t)N * 4);
  int*    chunk  = (int*)alloc((size_t)(NC + 1) * 4);
  int*    csr    = (int*)alloc((size_t)E * 4);
  float*  dinv   = (float*)alloc((size_t)N * 4);
  ushort* y      = (ushort*)alloc((size_t)N * 128 * 2);  // sliced for 128-wide; flat for 40
  float*  hpre   = (float*)alloc((size_t)N * 128 * 4);
  float*  ps     = (float*)alloc((size_t)256 * 128 * 4);
  float*  pss    = (float*)alloc((size_t)256 * 128 * 4);
  float*  scl    = (float*)alloc(128 * 4);
  float*  shf    = (float*)alloc(128 * 4);
  int*    hmatT  = (int*)alloc((size_t)NB * NBLK * 4);
  int*    hbaseT = (int*)alloc((size_t)NB * NBLK * 4);
  int*    boff   = (int*)alloc((size_t)(NB + 1) * 4);
  uint*   ebuf   = (uint*)hpre;  // alias: prep finishes before hpre is written

  // graph prep: radix partition (no global atomics)
  histA_k<<<NBLK, 256, 0, stream>>>(ei, E, hmatT);
  scanM_k<<<1, 256, 0, stream>>>(hmatT, hbaseT, boff, E);
  partB_k<<<NBLK, 256, 0, stream>>>(ei, E, hbaseT, ebuf);
  histnode_k<<<NB, 256, 0, stream>>>(ebuf, boff, deg, N);
  scanA_k<<<NC, 256, 0, stream>>>(deg, rowst, chunk, N);
  scanB_k<<<1, 512, 0, stream>>>(chunk, NC);
  scanC_k<<<NC, 256, 0, stream>>>(deg, chunk, rowst, N);
  dinv_k<<<(N + 255) / 256, 256, 0, stream>>>(deg, dinv, N);
  fillB_k<<<NB, 256, 0, stream>>>(ebuf, boff, rowst, csr, N, E);

  const int GB = (N + 63) / 64;        // 1563
  const int AB128 = 8 * GB;            // 12504: 8 col-groups x 64-node blocks
  const int AB40 = (N + 3) / 4;        // 25000

  // layer 1
  gemm_mfma_k<128, false><<<GB, 256, 0, stream>>>(x, W1, nullptr, nullptr, dinv, y, N);
  agg128_k<<<AB128, 256, 0, stream>>>((const uint*)y, csr, rowst, deg, dinv, b1, hpre, N);
  stats_partial_k<<<256, 256, 0, stream>>>(hpre, ps, pss, N);
  stats_final_k<<<1, 128, 0, stream>>>(ps, pss, g1, be1, scl, shf, N);
  // layer 2
  gemm_mfma_k<128, true><<<GB, 256, 0, stream>>>(hpre, W2, scl, shf, dinv, y, N);
  agg128_k<<<AB128, 256, 0, stream>>>((const uint*)y, csr, rowst, deg, dinv, b2, hpre, N);
  stats_partial_k<<<256, 256, 0, stream>>>(hpre, ps, pss, N);
  stats_final_k<<<1, 128, 0, stream>>>(ps, pss, g2, be2, scl, shf, N);
  // layer 3 + log_softmax
  gemm_mfma_k<40, true><<<GB, 256, 0, stream>>>(hpre, W3, scl, shf, dinv, y, N);
  agg40_lsm_k<<<AB40, 256, 0, stream>>>(y, csr, rowst, deg, dinv, b3, outp, N);
}

// Round 9
// 587.140 us; speedup vs baseline: 1.1256x; 1.1256x over previous
//
#include <hip/hip_runtime.h>
#include <hip/hip_bf16.h>
#include <math.h>

#define NNODES 100000
#define EPSV 1e-5f
#define NB 391          // ceil(100000/256) buckets of 256 nodes
#define NBLK 256        // partition blocks (histA/partB ranges must match)

typedef __attribute__((ext_vector_type(8))) short short8v;   // 8 bf16 = 4 VGPR
typedef __attribute__((ext_vector_type(4))) float f32x4;

__device__ __forceinline__ ushort f2bf(float f) {
  uint u = __float_as_uint(f);
  return (ushort)((u + 0x7fffu + ((u >> 16) & 1u)) >> 16);  // RNE
}
__device__ __forceinline__ float bf2f(ushort h) { return __uint_as_float(((uint)h) << 16); }

// swizzled LDS offset for tiles with 256B rows: XOR 16B-granule index with row&7
__device__ __forceinline__ int lds_off(int row, int byteInRow) {
  return row * 256 + ((((byteInRow >> 4) ^ (row & 7)) << 4) | (byteInRow & 15));
}

// ---------------- W image precompute: Wimg[c*128+k] = bf16(W[k*NREAL+c]), pad c>=NREAL ----------------

template <int NREAL>
__global__ __launch_bounds__(256) void wimg_k(const float* __restrict__ W, ushort* __restrict__ img) {
  int idx = blockIdx.x * 256 + threadIdx.x;   // = c*128 + k
  int c = idx >> 7, k = idx & 127;
  img[idx] = (c < NREAL) ? f2bf(W[k * NREAL + c]) : (ushort)0;
}

// ---------------- graph prep: radix partition, no global atomics ----------------

__global__ __launch_bounds__(256) void histA_k(const int* __restrict__ ei, int E,
                                               int* __restrict__ hmatT) {
  __shared__ int lh[NB];
  for (int i = threadIdx.x; i < NB; i += 256) lh[i] = 0;
  __syncthreads();
  int per = (E + NBLK - 1) / NBLK;
  int s0 = blockIdx.x * per, s1 = min(E, s0 + per);
  for (int e = s0 + threadIdx.x; e < s1; e += 256)
    atomicAdd(&lh[ei[E + e] >> 8], 1);
  __syncthreads();
  for (int i = threadIdx.x; i < NB; i += 256)
    hmatT[i * NBLK + blockIdx.x] = lh[i];
}

// parallel per-bucket scan: block i scans its contiguous 256-row; total -> btot[i]
__global__ __launch_bounds__(256) void scanM1_k(const int* __restrict__ hmatT,
                                                int* __restrict__ hbaseT,
                                                int* __restrict__ btot) {
  __shared__ int sm[256];
  int i = blockIdx.x, t = threadIdx.x;
  int v = hmatT[i * NBLK + t];
  sm[t] = v;
  __syncthreads();
  for (int off = 1; off < 256; off <<= 1) {
    int u = (t >= off) ? sm[t - off] : 0;
    __syncthreads();
    sm[t] += u;
    __syncthreads();
  }
  hbaseT[i * NBLK + t] = sm[t] - v;    // exclusive within bucket
  if (t == 255) btot[i] = sm[255];
}

// exclusive scan of NB bucket totals (1 block, 512 threads)
__global__ __launch_bounds__(512) void scanM2_k(const int* __restrict__ btot,
                                                int* __restrict__ boff, int E) {
  __shared__ int sm[512];
  int t = threadIdx.x;
  int v = (t < NB) ? btot[t] : 0;
  sm[t] = v;
  __syncthreads();
  for (int off = 1; off < 512; off <<= 1) {
    int u = (t >= off) ? sm[t - off] : 0;
    __syncthreads();
    sm[t] += u;
    __syncthreads();
  }
  if (t < NB) boff[t] = sm[t] - v;
  if (t == 0) boff[NB] = E;
}

// scatter edges to bucket-grouped ebuf via private LDS cursors.
// packed word: (dst & 255) << 17 | src   (src < 2^17)
__global__ __launch_bounds__(256) void partB_k(const int* __restrict__ ei, int E,
                                               const int* __restrict__ hbaseT,
                                               const int* __restrict__ boff,
                                               uint* __restrict__ ebuf) {
  __shared__ int cur[NB];
  for (int i = threadIdx.x; i < NB; i += 256)
    cur[i] = hbaseT[i * NBLK + blockIdx.x] + boff[i];
  __syncthreads();
  int per = (E + NBLK - 1) / NBLK;
  int s0 = blockIdx.x * per, s1 = min(E, s0 + per);
  for (int e = s0 + threadIdx.x; e < s1; e += 256) {
    int s = ei[e];
    int d = ei[E + e];
    int p = atomicAdd(&cur[d >> 8], 1);
    ebuf[p] = ((uint)(d & 255) << 17) | (uint)s;
  }
}

__global__ __launch_bounds__(256) void histnode_k(const uint* __restrict__ ebuf,
                                                  const int* __restrict__ boff,
                                                  int* __restrict__ deg, int n) {
  __shared__ int h[256];
  int b = blockIdx.x;
  h[threadIdx.x] = 0;
  __syncthreads();
  int s0 = boff[b], s1 = boff[b + 1];
  for (int i = s0 + threadIdx.x; i < s1; i += 256)
    atomicAdd(&h[ebuf[i] >> 17], 1);
  __syncthreads();
  int node = b * 256 + threadIdx.x;
  if (node < n) deg[node] = h[threadIdx.x];
}

__global__ __launch_bounds__(256) void scanA_k(const int* __restrict__ cnt, int* __restrict__ rowst,
                                               int* __restrict__ chunk, int n) {
  __shared__ int sm[256];
  int i = blockIdx.x * 256 + threadIdx.x;
  int v = (i < n) ? cnt[i] : 0;
  sm[threadIdx.x] = v;
  __syncthreads();
  for (int off = 1; off < 256; off <<= 1) {
    int t = (threadIdx.x >= off) ? sm[threadIdx.x - off] : 0;
    __syncthreads();
    sm[threadIdx.x] += t;
    __syncthreads();
  }
  if (i < n) rowst[i] = sm[threadIdx.x];
  if (threadIdx.x == 255) chunk[blockIdx.x] = sm[255];
}

__global__ __launch_bounds__(512) void scanB_k(int* __restrict__ chunk, int nc) {
  __shared__ int sm[512];
  int v = (threadIdx.x < nc) ? chunk[threadIdx.x] : 0;
  sm[threadIdx.x] = v;
  __syncthreads();
  for (int off = 1; off < 512; off <<= 1) {
    int t = (threadIdx.x >= off) ? sm[threadIdx.x - off] : 0;
    __syncthreads();
    sm[threadIdx.x] += t;
    __syncthreads();
  }
  if (threadIdx.x < nc) chunk[threadIdx.x] = sm[threadIdx.x] - v;
}

__global__ __launch_bounds__(256) void scanC_k(const int* __restrict__ cnt, const int* __restrict__ chunk,
                                               int* __restrict__ rowst, int n) {
  int i = blockIdx.x * 256 + threadIdx.x;
  if (i < n) rowst[i] = chunk[blockIdx.x] + rowst[i] - cnt[i];
}

__global__ __launch_bounds__(256) void dinv_k(const int* __restrict__ deg, float* __restrict__ dinv, int n) {
  int i = blockIdx.x * 256 + threadIdx.x;
  if (i < n) dinv[i] = rsqrtf((float)deg[i] + 1.0f);
}

__global__ __launch_bounds__(256) void fillB_k(const uint* __restrict__ ebuf,
                                               const int* __restrict__ boff,
                                               const int* __restrict__ rowst,
                                               int* __restrict__ csr, int n, int E) {
  __shared__ int rst[256];
  __shared__ int cur[256];
  int b = blockIdx.x;
  int node = b * 256 + threadIdx.x;
  rst[threadIdx.x] = (node < n) ? rowst[node] : E;
  cur[threadIdx.x] = 0;
  __syncthreads();
  int s0 = boff[b], s1 = boff[b + 1];
  for (int i = s0 + threadIdx.x; i < s1; i += 256) {
    uint w = ebuf[i];
    int l = w >> 17;
    int p = atomicAdd(&cur[l], 1);
    csr[rst[l] + p] = (int)(w & 0x1FFFFu);
  }
}

// ---------------- MFMA GEMM: y_bf16[r][c] = dinv[r] * sum_k z[r][k] * W[k][c] ----------------
// A staged in LDS (swizzled, reused as output tile). B fragments read directly from
// the precomputed global bf16 W image (L2-resident, 1563x reuse).

template <int NREAL, bool BN>
__global__ __launch_bounds__(256) void gemm_mfma_k(const float* __restrict__ in, const ushort* __restrict__ Wimg,
                                                   const float* __restrict__ scale, const float* __restrict__ shift,
                                                   const float* __restrict__ dinv, ushort* __restrict__ y, int n) {
  constexpr int NT = (NREAL + 15) / 16;  // col tiles: 8 or 3
  __shared__ ushort At[64 * 128];        // swizzled A tile; reused as output tile
  const int tid = threadIdx.x;
  const int row0 = blockIdx.x * 64;

  // stage A tile: BN+ReLU fused, cvt bf16
#pragma unroll
  for (int it = 0; it < 8; ++it) {
    int f = tid + it * 256;
    int r = f >> 5, c4 = (f & 31) * 4;
    int row = row0 + r;
    float4 v;
    if (row < n) v = *(const float4*)&in[(size_t)row * 128 + c4];
    else v = make_float4(0.f, 0.f, 0.f, 0.f);
    if (BN) {
      float4 sc = *(const float4*)&scale[c4];
      float4 sh = *(const float4*)&shift[c4];
      v.x = fmaxf(fmaf(v.x, sc.x, sh.x), 0.f);
      v.y = fmaxf(fmaf(v.y, sc.y, sh.y), 0.f);
      v.z = fmaxf(fmaf(v.z, sc.z, sh.z), 0.f);
      v.w = fmaxf(fmaf(v.w, sc.w, sh.w), 0.f);
    }
    ushort4 h;
    h.x = f2bf(v.x); h.y = f2bf(v.y); h.z = f2bf(v.z); h.w = f2bf(v.w);
    *(ushort4*)((char*)At + lds_off(r, c4 * 2)) = h;
  }
  __syncthreads();

  const int w = tid >> 6, lane = tid & 63;
  const int lr = lane & 15, g = lane >> 4;

  short8v a[4];
#pragma unroll
  for (int kk = 0; kk < 4; ++kk)
    a[kk] = *(const short8v*)((const char*)At + lds_off(w * 16 + lr, kk * 64 + g * 16));
  float dv[4];
#pragma unroll
  for (int i = 0; i < 4; ++i) {
    int rr = row0 + w * 16 + g * 4 + i;
    dv[i] = (rr < n) ? dinv[rr] : 0.f;
  }
  __syncthreads();  // all waves done reading At -> reuse as output tile

#pragma unroll
  for (int ct = 0; ct < NT; ++ct) {
    f32x4 acc = {0.f, 0.f, 0.f, 0.f};
#pragma unroll
    for (int kk = 0; kk < 4; ++kk) {
      short8v b = *(const short8v*)&Wimg[(ct * 16 + lr) * 128 + kk * 32 + g * 8];
      acc = __builtin_amdgcn_mfma_f32_16x16x32_bf16(a[kk], b, acc, 0, 0, 0);
    }
    // C/D layout: col = lane&15, row = (lane>>4)*4 + i
#pragma unroll
    for (int i = 0; i < 4; ++i)
      *(ushort*)((char*)At + lds_off(w * 16 + g * 4 + i, (ct * 16 + lr) * 2)) = f2bf(acc[i] * dv[i]);
  }
  __syncthreads();

  if constexpr (NREAL == 128) {
#pragma unroll
    for (int it = 0; it < 4; ++it) {
      int cid = tid + it * 256;
      int r = cid >> 4, gg = cid & 15;
      int row = row0 + r;
      if (row < n) {
        short8v t = *(const short8v*)((const char*)At + lds_off(r, gg * 16));
        *(short8v*)&y[(size_t)row * 128 + gg * 8] = t;
      }
    }
  } else {
#pragma unroll
    for (int it = 0; it < 3; ++it) {
      int cid = tid + it * 256;
      if (cid < 640) {
        int r = cid / 10, u = cid - r * 10;
        int row = row0 + r;
        if (row < n) {
          ushort4 t = *(const ushort4*)((const char*)At + lds_off(r, u * 8));
          *(ushort4*)&y[(size_t)row * 40 + u * 4] = t;
        }
      }
    }
  }
}

// ---------------- aggregation (flat bf16 y, full 256B-row gathers, 8-deep) ----------------

__global__ __launch_bounds__(256) void agg128_k(const ushort* __restrict__ y, const int* __restrict__ csr,
                                                const int* __restrict__ rowst, const int* __restrict__ deg,
                                                const float* __restrict__ dinv, const float* __restrict__ bias,
                                                float* __restrict__ out, int n) {
  int wid = (blockIdx.x * 256 + threadIdx.x) >> 6;
  if (wid >= n) return;
  int lane = threadIdx.x & 63;
  int base = rowst[wid];
  int dg = deg[wid];
  const uint* yu = (const uint*)y;      // 64 uints (128 bf16) per row
  float p0[8], p1[8];
#pragma unroll
  for (int j = 0; j < 8; ++j) { p0[j] = 0.f; p1[j] = 0.f; }
  int t = 0;
  for (; t + 8 <= dg; t += 8) {
    int sidx[8];
#pragma unroll
    for (int j = 0; j < 8; ++j) sidx[j] = csr[base + t + j];
    uint v[8];
#pragma unroll
    for (int j = 0; j < 8; ++j) v[j] = yu[(size_t)sidx[j] * 64 + lane];
#pragma unroll
    for (int j = 0; j < 8; ++j) {
      p0[j] += __uint_as_float(v[j] << 16);
      p1[j] += __uint_as_float(v[j] & 0xffff0000u);
    }
  }
  for (; t < dg; ++t) {
    int s = csr[base + t];
    uint v = yu[(size_t)s * 64 + lane];
    p0[0] += __uint_as_float(v << 16);
    p1[0] += __uint_as_float(v & 0xffff0000u);
  }
  uint vs = yu[(size_t)wid * 64 + lane];
  p0[0] += __uint_as_float(vs << 16);
  p1[0] += __uint_as_float(vs & 0xffff0000u);
  float s0 = ((p0[0] + p0[1]) + (p0[2] + p0[3])) + ((p0[4] + p0[5]) + (p0[6] + p0[7]));
  float s1 = ((p1[0] + p1[1]) + (p1[2] + p1[3])) + ((p1[4] + p1[5]) + (p1[6] + p1[7]));
  float dvv = dinv[wid];
  float2 bb = *(const float2*)&bias[lane * 2];
  float2 o;
  o.x = fmaf(s0, dvv, bb.x);
  o.y = fmaf(s1, dvv, bb.y);
  *(float2*)&out[(size_t)wid * 128 + lane * 2] = o;
}

// ---------------- last layer: aggregation (d=40) + bias + log_softmax ----------------

__global__ __launch_bounds__(256) void agg40_lsm_k(const ushort* __restrict__ y, const int* __restrict__ csr,
                                                   const int* __restrict__ rowst, const int* __restrict__ deg,
                                                   const float* __restrict__ dinv, const float* __restrict__ bias,
                                                   float* __restrict__ out, int n) {
  int wid = (blockIdx.x * 256 + threadIdx.x) >> 6;
  if (wid >= n) return;
  int lane = threadIdx.x & 63;
  int col = lane < 40 ? lane : 39;
  int base = rowst[wid];
  int dg = deg[wid];
  float a = 0.f, b = 0.f, c = 0.f, d = 0.f;
  int t = 0;
  for (; t + 4 <= dg; t += 4) {
    int s0 = csr[base + t], s1 = csr[base + t + 1], s2 = csr[base + t + 2], s3 = csr[base + t + 3];
    a += bf2f(y[(size_t)s0 * 40 + col]);
    b += bf2f(y[(size_t)s1 * 40 + col]);
    c += bf2f(y[(size_t)s2 * 40 + col]);
    d += bf2f(y[(size_t)s3 * 40 + col]);
  }
  for (; t < dg; ++t) {
    int s = csr[base + t];
    a += bf2f(y[(size_t)s * 40 + col]);
  }
  a += bf2f(y[(size_t)wid * 40 + col]);
  float v = fmaf((a + b) + (c + d), dinv[wid], bias[col]);
  bool act = lane < 40;
  float m = act ? v : -INFINITY;
#pragma unroll
  for (int off = 32; off; off >>= 1) m = fmaxf(m, __shfl_xor(m, off));
  float e = act ? expf(v - m) : 0.f;
  float se = e;
#pragma unroll
  for (int off = 32; off; off >>= 1) se += __shfl_xor(se, off);
  if (act) out[(size_t)wid * 40 + lane] = v - m - logf(se);
}

// ---------------- BN stats ----------------

__global__ __launch_bounds__(256) void stats_partial_k(const float* __restrict__ h,
                                                       float* __restrict__ ps, float* __restrict__ pss, int n) {
  int c = threadIdx.x & 127;
  int half = threadIdx.x >> 7;
  int r0 = blockIdx.x * 2 + half;
  float s = 0.f, ss = 0.f;
  for (int r = r0; r < n; r += 512) {
    float v = h[(size_t)r * 128 + c];
    s += v;
    ss = fmaf(v, v, ss);
  }
  __shared__ float sm[256], sm2[256];
  sm[threadIdx.x] = s;
  sm2[threadIdx.x] = ss;
  __syncthreads();
  if (threadIdx.x < 128) {
    ps[blockIdx.x * 128 + c] = sm[c] + sm[c + 128];
    pss[blockIdx.x * 128 + c] = sm2[c] + sm2[c + 128];
  }
}

__global__ __launch_bounds__(128) void stats_final_k(const float* __restrict__ ps, const float* __restrict__ pss,
                                                     const float* __restrict__ g, const float* __restrict__ be,
                                                     float* __restrict__ scale, float* __restrict__ shift, int n) {
  int c = threadIdx.x;
  float s = 0.f, ss = 0.f;
  for (int b = 0; b < 256; ++b) {
    s += ps[b * 128 + c];
    ss += pss[b * 128 + c];
  }
  float mu = s / (float)n;
  float var = ss / (float)n - mu * mu;
  float rs = rsqrtf(var + EPSV);
  float sc = rs * g[c];
  scale[c] = sc;
  shift[c] = fmaf(-mu, sc, be[c]);
}

// ---------------- launch ----------------

extern "C" void kernel_launch(void* const* d_in, const int* in_sizes, int n_in,
                              void* d_out, int out_size, void* d_ws, size_t ws_size,
                              hipStream_t stream) {
  const float* x   = (const float*)d_in[0];
  const int*   ei  = (const int*)d_in[1];
  const float* W1  = (const float*)d_in[2];
  const float* b1  = (const float*)d_in[3];
  const float* W2  = (const float*)d_in[4];
  const float* b2  = (const float*)d_in[5];
  const float* W3  = (const float*)d_in[6];
  const float* b3  = (const float*)d_in[7];
  const float* g1  = (const float*)d_in[8];
  const float* be1 = (const float*)d_in[9];
  const float* g2  = (const float*)d_in[10];
  const float* be2 = (const float*)d_in[11];
  float* outp = (float*)d_out;

  const int N = NNODES;
  const int E = in_sizes[1] / 2;
  const int NC = (N + 255) / 256;  // 391 (node-scan chunks)

  char* w = (char*)d_ws;
  auto alloc = [&](size_t bytes) -> void* {
    void* p = (void*)w;
    w += (bytes + 255) & ~(size_t)255;
    return p;
  };
  int*    deg    = (int*)alloc((size_t)N * 4);
  int*    rowst  = (int*)alloc((size_t)N * 4);
  int*    chunk  = (int*)alloc((size_t)(NC + 1) * 4);
  int*    csr    = (int*)alloc((size_t)E * 4);
  float*  dinv   = (float*)alloc((size_t)N * 4);
  ushort* y      = (ushort*)alloc((size_t)N * 128 * 2);  // flat bf16 y
  float*  hpre   = (float*)alloc((size_t)N * 128 * 4);
  float*  ps     = (float*)alloc((size_t)256 * 128 * 4);
  float*  pss    = (float*)alloc((size_t)256 * 128 * 4);
  float*  scl    = (float*)alloc(128 * 4);
  float*  shf    = (float*)alloc(128 * 4);
  int*    hmatT  = (int*)alloc((size_t)NB * NBLK * 4);
  int*    hbaseT = (int*)alloc((size_t)NB * NBLK * 4);
  int*    btot   = (int*)alloc((size_t)NB * 4);
  int*    boff   = (int*)alloc((size_t)(NB + 1) * 4);
  ushort* Wimg1  = (ushort*)alloc((size_t)128 * 128 * 2);
  ushort* Wimg2  = (ushort*)alloc((size_t)128 * 128 * 2);
  ushort* Wimg3  = (ushort*)alloc((size_t)48 * 128 * 2);
  uint*   ebuf   = (uint*)hpre;  // alias: prep finishes before hpre is written

  // W images (bf16, transposed [c][k], padded)
  wimg_k<128><<<64, 256, 0, stream>>>(W1, Wimg1);
  wimg_k<128><<<64, 256, 0, stream>>>(W2, Wimg2);
  wimg_k<40><<<24, 256, 0, stream>>>(W3, Wimg3);

  // graph prep: radix partition (no global atomics, parallel scans)
  histA_k<<<NBLK, 256, 0, stream>>>(ei, E, hmatT);
  scanM1_k<<<NB, 256, 0, stream>>>(hmatT, hbaseT, btot);
  scanM2_k<<<1, 512, 0, stream>>>(btot, boff, E);
  partB_k<<<NBLK, 256, 0, stream>>>(ei, E, hbaseT, boff, ebuf);
  histnode_k<<<NB, 256, 0, stream>>>(ebuf, boff, deg, N);
  scanA_k<<<NC, 256, 0, stream>>>(deg, rowst, chunk, N);
  scanB_k<<<1, 512, 0, stream>>>(chunk, NC);
  scanC_k<<<NC, 256, 0, stream>>>(deg, chunk, rowst, N);
  dinv_k<<<(N + 255) / 256, 256, 0, stream>>>(deg, dinv, N);
  fillB_k<<<NB, 256, 0, stream>>>(ebuf, boff, rowst, csr, N, E);

  const int GB = (N + 63) / 64;  // 1563
  const int AB = (N + 3) / 4;    // 25000

  // layer 1
  gemm_mfma_k<128, false><<<GB, 256, 0, stream>>>(x, Wimg1, nullptr, nullptr, dinv, y, N);
  agg128_k<<<AB, 256, 0, stream>>>(y, csr, rowst, deg, dinv, b1, hpre, N);
  stats_partial_k<<<256, 256, 0, stream>>>(hpre, ps, pss, N);
  stats_final_k<<<1, 128, 0, stream>>>(ps, pss, g1, be1, scl, shf, N);
  // layer 2
  gemm_mfma_k<128, true><<<GB, 256, 0, stream>>>(hpre, Wimg2, scl, shf, dinv, y, N);
  agg128_k<<<AB, 256, 0, stream>>>(y, csr, rowst, deg, dinv, b2, hpre, N);
  stats_partial_k<<<256, 256, 0, stream>>>(hpre, ps, pss, N);
  stats_final_k<<<1, 128, 0, stream>>>(ps, pss, g2, be2, scl, shf, N);
  // layer 3 + log_softmax
  gemm_mfma_k<40, true><<<GB, 256, 0, stream>>>(hpre, Wimg3, scl, shf, dinv, y, N);
  agg40_lsm_k<<<AB, 256, 0, stream>>>(y, csr, rowst, deg, dinv, b3, outp, N);
}

// Round 12
// 528.613 us; speedup vs baseline: 1.2502x; 1.1107x over previous
//
#include <hip/hip_runtime.h>
#include <hip/hip_bf16.h>
#include <math.h>

#define NNODES 100000
#define EPSV 1e-5f
#define NB 391          // ceil(100000/256) buckets of 256 nodes
#define NBLK 256        // partition blocks (histA/partB ranges must match)

typedef __attribute__((ext_vector_type(8))) short short8v;   // 8 bf16 = 4 VGPR
typedef __attribute__((ext_vector_type(4))) float f32x4;

__device__ __forceinline__ ushort f2bf(float f) {
  uint u = __float_as_uint(f);
  return (ushort)((u + 0x7fffu + ((u >> 16) & 1u)) >> 16);  // RNE
}
__device__ __forceinline__ float bf2f(ushort h) { return __uint_as_float(((uint)h) << 16); }

// swizzled LDS offset for tiles with 256B rows: XOR 16B-granule index with row&7
__device__ __forceinline__ int lds_off(int row, int byteInRow) {
  return row * 256 + ((((byteInRow >> 4) ^ (row & 7)) << 4) | (byteInRow & 15));
}

// ---------------- W images (one kernel): img[c*128+k] = bf16(W[k*NREAL+c]) ----------------

__global__ __launch_bounds__(256) void wimg_all_k(const float* __restrict__ W1, const float* __restrict__ W2,
                                                  const float* __restrict__ W3, ushort* __restrict__ i1,
                                                  ushort* __restrict__ i2, ushort* __restrict__ i3) {
  int b = blockIdx.x, tid = threadIdx.x;
  if (b < 64) {
    int idx = b * 256 + tid, c = idx >> 7, k = idx & 127;
    i1[idx] = f2bf(W1[k * 128 + c]);
  } else if (b < 128) {
    int idx = (b - 64) * 256 + tid, c = idx >> 7, k = idx & 127;
    i2[idx] = f2bf(W2[k * 128 + c]);
  } else {
    int idx = (b - 128) * 256 + tid, c = idx >> 7, k = idx & 127;
    i3[idx] = (c < 40) ? f2bf(W3[k * 40 + c]) : (ushort)0;
  }
}

// ---------------- graph prep: radix partition, no global atomics ----------------

__global__ __launch_bounds__(256) void histA_k(const int* __restrict__ ei, int E,
                                               int* __restrict__ hmatT) {
  __shared__ int lh[NB];
  for (int i = threadIdx.x; i < NB; i += 256) lh[i] = 0;
  __syncthreads();
  int per = (E + NBLK - 1) / NBLK;
  int s0 = blockIdx.x * per, s1 = min(E, s0 + per);
  for (int e = s0 + threadIdx.x; e < s1; e += 256)
    atomicAdd(&lh[ei[E + e] >> 8], 1);
  __syncthreads();
  for (int i = threadIdx.x; i < NB; i += 256)
    hmatT[i * NBLK + blockIdx.x] = lh[i];
}

__global__ __launch_bounds__(256) void scanM1_k(const int* __restrict__ hmatT,
                                                int* __restrict__ hbaseT,
                                                int* __restrict__ btot) {
  __shared__ int sm[256];
  int i = blockIdx.x, t = threadIdx.x;
  int v = hmatT[i * NBLK + t];
  sm[t] = v;
  __syncthreads();
  for (int off = 1; off < 256; off <<= 1) {
    int u = (t >= off) ? sm[t - off] : 0;
    __syncthreads();
    sm[t] += u;
    __syncthreads();
  }
  hbaseT[i * NBLK + t] = sm[t] - v;    // exclusive within bucket
  if (t == 255) btot[i] = sm[255];
}

__global__ __launch_bounds__(512) void scanM2_k(const int* __restrict__ btot,
                                                int* __restrict__ boff, int E) {
  __shared__ int sm[512];
  int t = threadIdx.x;
  int v = (t < NB) ? btot[t] : 0;
  sm[t] = v;
  __syncthreads();
  for (int off = 1; off < 512; off <<= 1) {
    int u = (t >= off) ? sm[t - off] : 0;
    __syncthreads();
    sm[t] += u;
    __syncthreads();
  }
  if (t < NB) boff[t] = sm[t] - v;
  if (t == 0) boff[NB] = E;
}

// packed word: (dst & 255) << 17 | src   (src < 2^17)
__global__ __launch_bounds__(256) void partB_k(const int* __restrict__ ei, int E,
                                               const int* __restrict__ hbaseT,
                                               const int* __restrict__ boff,
                                               uint* __restrict__ ebuf) {
  __shared__ int cur[NB];
  for (int i = threadIdx.x; i < NB; i += 256)
    cur[i] = hbaseT[i * NBLK + blockIdx.x] + boff[i];
  __syncthreads();
  int per = (E + NBLK - 1) / NBLK;
  int s0 = blockIdx.x * per, s1 = min(E, s0 + per);
  for (int e = s0 + threadIdx.x; e < s1; e += 256) {
    int s = ei[e];
    int d = ei[E + e];
    int p = atomicAdd(&cur[d >> 8], 1);
    ebuf[p] = ((uint)(d & 255) << 17) | (uint)s;
  }
}

__global__ __launch_bounds__(256) void histnode_k(const uint* __restrict__ ebuf,
                                                  const int* __restrict__ boff,
                                                  int* __restrict__ deg, int n) {
  __shared__ int h[256];
  int b = blockIdx.x;
  h[threadIdx.x] = 0;
  __syncthreads();
  int s0 = boff[b], s1 = boff[b + 1];
  for (int i = s0 + threadIdx.x; i < s1; i += 256)
    atomicAdd(&h[ebuf[i] >> 17], 1);
  __syncthreads();
  int node = b * 256 + threadIdx.x;
  if (node < n) deg[node] = h[threadIdx.x];
}

__global__ __launch_bounds__(256) void scanA_k(const int* __restrict__ cnt, int* __restrict__ rowst,
                                               int* __restrict__ chunk, int n) {
  __shared__ int sm[256];
  int i = blockIdx.x * 256 + threadIdx.x;
  int v = (i < n) ? cnt[i] : 0;
  sm[threadIdx.x] = v;
  __syncthreads();
  for (int off = 1; off < 256; off <<= 1) {
    int t = (threadIdx.x >= off) ? sm[threadIdx.x - off] : 0;
    __syncthreads();
    sm[threadIdx.x] += t;
    __syncthreads();
  }
  if (i < n) rowst[i] = sm[threadIdx.x];
  if (threadIdx.x == 255) chunk[blockIdx.x] = sm[255];
}

__global__ __launch_bounds__(512) void scanB_k(int* __restrict__ chunk, int nc) {
  __shared__ int sm[512];
  int v = (threadIdx.x < nc) ? chunk[threadIdx.x] : 0;
  sm[threadIdx.x] = v;
  __syncthreads();
  for (int off = 1; off < 512; off <<= 1) {
    int t = (threadIdx.x >= off) ? sm[threadIdx.x - off] : 0;
    __syncthreads();
    sm[threadIdx.x] += t;
    __syncthreads();
  }
  if (threadIdx.x < nc) chunk[threadIdx.x] = sm[threadIdx.x] - v;
}

// rowst finalize + dinv fused
__global__ __launch_bounds__(256) void scanC_k(const int* __restrict__ cnt, const int* __restrict__ chunk,
                                               int* __restrict__ rowst, float* __restrict__ dinv, int n) {
  int i = blockIdx.x * 256 + threadIdx.x;
  if (i < n) {
    rowst[i] = chunk[blockIdx.x] + rowst[i] - cnt[i];
    dinv[i] = rsqrtf((float)cnt[i] + 1.0f);
  }
}

__global__ __launch_bounds__(256) void fillB_k(const uint* __restrict__ ebuf,
                                               const int* __restrict__ boff,
                                               const int* __restrict__ rowst,
                                               int* __restrict__ csr, int n, int E) {
  __shared__ int rst[256];
  __shared__ int cur[256];
  int b = blockIdx.x;
  int node = b * 256 + threadIdx.x;
  rst[threadIdx.x] = (node < n) ? rowst[node] : E;
  cur[threadIdx.x] = 0;
  __syncthreads();
  int s0 = boff[b], s1 = boff[b + 1];
  for (int i = s0 + threadIdx.x; i < s1; i += 256) {
    uint w = ebuf[i];
    int l = w >> 17;
    int p = atomicAdd(&cur[l], 1);
    csr[rst[l] + p] = (int)(w & 0x1FFFFu);
  }
}

// ---------------- MFMA GEMM: y_bf16[r][c] = dinv[r] * sum_k z[r][k] * W[k][c] ----------------
// TIN = float (layer1) or ushort/bf16 (layers 2,3). B from global bf16 W image (L2-resident).

template <int NREAL, bool BN, typename TIN>
__global__ __launch_bounds__(256) void gemm_mfma_k(const TIN* __restrict__ in, const ushort* __restrict__ Wimg,
                                                   const float* __restrict__ scale, const float* __restrict__ shift,
                                                   const float* __restrict__ dinv, ushort* __restrict__ y, int n) {
  constexpr int NT = (NREAL + 15) / 16;  // col tiles: 8 or 3
  __shared__ ushort At[64 * 128];        // swizzled A tile; reused as output tile
  const int tid = threadIdx.x;
  const int row0 = blockIdx.x * 64;

  if constexpr (sizeof(TIN) == 4) {      // fp32 input
#pragma unroll
    for (int it = 0; it < 8; ++it) {
      int f = tid + it * 256;
      int r = f >> 5, c4 = (f & 31) * 4;
      int row = row0 + r;
      float4 v;
      if (row < n) v = *(const float4*)&((const float*)in)[(size_t)row * 128 + c4];
      else v = make_float4(0.f, 0.f, 0.f, 0.f);
      if (BN) {
        float4 sc = *(const float4*)&scale[c4];
        float4 sh = *(const float4*)&shift[c4];
        v.x = fmaxf(fmaf(v.x, sc.x, sh.x), 0.f);
        v.y = fmaxf(fmaf(v.y, sc.y, sh.y), 0.f);
        v.z = fmaxf(fmaf(v.z, sc.z, sh.z), 0.f);
        v.w = fmaxf(fmaf(v.w, sc.w, sh.w), 0.f);
      }
      ushort4 h;
      h.x = f2bf(v.x); h.y = f2bf(v.y); h.z = f2bf(v.z); h.w = f2bf(v.w);
      *(ushort4*)((char*)At + lds_off(r, c4 * 2)) = h;
    }
  } else {                               // bf16 input (BN path)
    const uint* inu = (const uint*)in;   // 64 uints per row
#pragma unroll
    for (int it = 0; it < 4; ++it) {
      int f = tid + it * 256;            // 0..1023, 16B chunks
      int r = f >> 4, c8 = (f & 15) * 8;
      int row = row0 + r;
      uint4 vv;
      if (row < n) vv = *(const uint4*)&inu[(size_t)row * 64 + (c8 >> 1)];
      else vv = make_uint4(0, 0, 0, 0);
      uint outw[4];
      const uint* vp = (const uint*)&vv;
#pragma unroll
      for (int j = 0; j < 4; ++j) {
        float lo = __uint_as_float(vp[j] << 16);
        float hi = __uint_as_float(vp[j] & 0xffff0000u);
        if (BN) {
          int c = c8 + j * 2;
          lo = fmaxf(fmaf(lo, scale[c], shift[c]), 0.f);
          hi = fmaxf(fmaf(hi, scale[c + 1], shift[c + 1]), 0.f);
        }
        outw[j] = ((uint)f2bf(hi) << 16) | (uint)f2bf(lo);
      }
      *(uint4*)((char*)At + lds_off(r, c8 * 2)) = *(uint4*)outw;
    }
  }
  __syncthreads();

  const int w = tid >> 6, lane = tid & 63;
  const int lr = lane & 15, g = lane >> 4;

  short8v a[4];
#pragma unroll
  for (int kk = 0; kk < 4; ++kk)
    a[kk] = *(const short8v*)((const char*)At + lds_off(w * 16 + lr, kk * 64 + g * 16));
  float dv[4];
#pragma unroll
  for (int i = 0; i < 4; ++i) {
    int rr = row0 + w * 16 + g * 4 + i;
    dv[i] = (rr < n) ? dinv[rr] : 0.f;
  }
  __syncthreads();  // all waves done reading At -> reuse as output tile

#pragma unroll
  for (int ct = 0; ct < NT; ++ct) {
    f32x4 acc = {0.f, 0.f, 0.f, 0.f};
#pragma unroll
    for (int kk = 0; kk < 4; ++kk) {
      short8v b = *(const short8v*)&Wimg[(ct * 16 + lr) * 128 + kk * 32 + g * 8];
      acc = __builtin_amdgcn_mfma_f32_16x16x32_bf16(a[kk], b, acc, 0, 0, 0);
    }
    // C/D layout: col = lane&15, row = (lane>>4)*4 + i
#pragma unroll
    for (int i = 0; i < 4; ++i)
      *(ushort*)((char*)At + lds_off(w * 16 + g * 4 + i, (ct * 16 + lr) * 2)) = f2bf(acc[i] * dv[i]);
  }
  __syncthreads();

  if constexpr (NREAL == 128) {
#pragma unroll
    for (int it = 0; it < 4; ++it) {
      int cid = tid + it * 256;
      int r = cid >> 4, gg = cid & 15;
      int row = row0 + r;
      if (row < n) {
        short8v t = *(const short8v*)((const char*)At + lds_off(r, gg * 16));
        *(short8v*)&y[(size_t)row * 128 + gg * 8] = t;
      }
    }
  } else {
#pragma unroll
    for (int it = 0; it < 3; ++it) {
      int cid = tid + it * 256;
      if (cid < 640) {
        int r = cid / 10, u = cid - r * 10;
        int row = row0 + r;
        if (row < n) {
          ushort4 t = *(const ushort4*)((const char*)At + lds_off(r, u * 8));
          *(ushort4*)&y[(size_t)row * 40 + u * 4] = t;
        }
      }
    }
  }
}

// ---------------- aggregation (flat bf16 y, 256B-row gathers, 8-deep; bf16 output) ----------------

__global__ __launch_bounds__(256) void agg128_k(const ushort* __restrict__ y, const int* __restrict__ csr,
                                                const int* __restrict__ rowst, const int* __restrict__ deg,
                                                const float* __restrict__ dinv, const float* __restrict__ bias,
                                                ushort* __restrict__ out, int n) {
  int wid = (blockIdx.x * 256 + threadIdx.x) >> 6;
  if (wid >= n) return;
  int lane = threadIdx.x & 63;
  int base = rowst[wid];
  int dg = deg[wid];
  const uint* yu = (const uint*)y;      // 64 uints (128 bf16) per row
  float p0[8], p1[8];
#pragma unroll
  for (int j = 0; j < 8; ++j) { p0[j] = 0.f; p1[j] = 0.f; }
  int t = 0;
  for (; t + 8 <= dg; t += 8) {
    int sidx[8];
#pragma unroll
    for (int j = 0; j < 8; ++j) sidx[j] = csr[base + t + j];
    uint v[8];
#pragma unroll
    for (int j = 0; j < 8; ++j) v[j] = yu[(size_t)sidx[j] * 64 + lane];
#pragma unroll
    for (int j = 0; j < 8; ++j) {
      p0[j] += __uint_as_float(v[j] << 16);
      p1[j] += __uint_as_float(v[j] & 0xffff0000u);
    }
  }
  for (; t < dg; ++t) {
    int s = csr[base + t];
    uint v = yu[(size_t)s * 64 + lane];
    p0[0] += __uint_as_float(v << 16);
    p1[0] += __uint_as_float(v & 0xffff0000u);
  }
  uint vs = yu[(size_t)wid * 64 + lane];
  p0[0] += __uint_as_float(vs << 16);
  p1[0] += __uint_as_float(vs & 0xffff0000u);
  float s0 = ((p0[0] + p0[1]) + (p0[2] + p0[3])) + ((p0[4] + p0[5]) + (p0[6] + p0[7]));
  float s1 = ((p1[0] + p1[1]) + (p1[2] + p1[3])) + ((p1[4] + p1[5]) + (p1[6] + p1[7]));
  float dvv = dinv[wid];
  float2 bb = *(const float2*)&bias[lane * 2];
  float ox = fmaf(s0, dvv, bb.x);
  float oy = fmaf(s1, dvv, bb.y);
  ((uint*)out)[(size_t)wid * 64 + lane] = ((uint)f2bf(oy) << 16) | (uint)f2bf(ox);
}

// ---------------- last layer: aggregation (d=40) + bias + log_softmax ----------------

__global__ __launch_bounds__(256) void agg40_lsm_k(const ushort* __restrict__ y, const int* __restrict__ csr,
                                                   const int* __restrict__ rowst, const int* __restrict__ deg,
                                                   const float* __restrict__ dinv, const float* __restrict__ bias,
                                                   float* __restrict__ out, int n) {
  int wid = (blockIdx.x * 256 + threadIdx.x) >> 6;
  if (wid >= n) return;
  int lane = threadIdx.x & 63;
  int col = lane < 40 ? lane : 39;
  int base = rowst[wid];
  int dg = deg[wid];
  float a = 0.f, b = 0.f, c = 0.f, d = 0.f;
  int t = 0;
  for (; t + 4 <= dg; t += 4) {
    int s0 = csr[base + t], s1 = csr[base + t + 1], s2 = csr[base + t + 2], s3 = csr[base + t + 3];
    a += bf2f(y[(size_t)s0 * 40 + col]);
    b += bf2f(y[(size_t)s1 * 40 + col]);
    c += bf2f(y[(size_t)s2 * 40 + col]);
    d += bf2f(y[(size_t)s3 * 40 + col]);
  }
  for (; t < dg; ++t) {
    int s = csr[base + t];
    a += bf2f(y[(size_t)s * 40 + col]);
  }
  a += bf2f(y[(size_t)wid * 40 + col]);
  float v = fmaf((a + b) + (c + d), dinv[wid], bias[col]);
  bool act = lane < 40;
  float m = act ? v : -INFINITY;
#pragma unroll
  for (int off = 32; off; off >>= 1) m = fmaxf(m, __shfl_xor(m, off));
  float e = act ? expf(v - m) : 0.f;
  float se = e;
#pragma unroll
  for (int off = 32; off; off >>= 1) se += __shfl_xor(se, off);
  if (act) out[(size_t)wid * 40 + lane] = v - m - logf(se);
}

// ---------------- BN stats (bf16 input, uint-vectorized) ----------------

__global__ __launch_bounds__(256) void stats_partial_k(const ushort* __restrict__ h,
                                                       float* __restrict__ ps, float* __restrict__ pss, int n) {
  int u = threadIdx.x & 63;    // col pair (cols 2u, 2u+1)
  int rg = threadIdx.x >> 6;   // 0..3
  const uint* hu = (const uint*)h;   // 64 uints per row
  float s0 = 0.f, ss0 = 0.f, s1 = 0.f, ss1 = 0.f;
  for (int r = blockIdx.x * 4 + rg; r < n; r += 1024) {
    uint v = hu[(size_t)r * 64 + u];
    float a = __uint_as_float(v << 16);
    float b = __uint_as_float(v & 0xffff0000u);
    s0 += a; ss0 = fmaf(a, a, ss0);
    s1 += b; ss1 = fmaf(b, b, ss1);
  }
  __shared__ float sA[256], sB[256], qA[256], qB[256];
  sA[threadIdx.x] = s0; sB[threadIdx.x] = s1;
  qA[threadIdx.x] = ss0; qB[threadIdx.x] = ss1;
  __syncthreads();
  if (threadIdx.x < 64) {
    float ta = sA[u] + sA[u + 64] + sA[u + 128] + sA[u + 192];
    float tb = sB[u] + sB[u + 64] + sB[u + 128] + sB[u + 192];
    float ua = qA[u] + qA[u + 64] + qA[u + 128] + qA[u + 192];
    float ub = qB[u] + qB[u + 64] + qB[u + 128] + qB[u + 192];
    ps[blockIdx.x * 128 + u * 2] = ta;
    ps[blockIdx.x * 128 + u * 2 + 1] = tb;
    pss[blockIdx.x * 128 + u * 2] = ua;
    pss[blockIdx.x * 128 + u * 2 + 1] = ub;
  }
}

__global__ __launch_bounds__(128) void stats_final_k(const float* __restrict__ ps, const float* __restrict__ pss,
                                                     const float* __restrict__ g, const float* __restrict__ be,
                                                     float* __restrict__ scale, float* __restrict__ shift, int n) {
  int c = threadIdx.x;
  float s = 0.f, ss = 0.f;
  for (int b = 0; b < 256; ++b) {
    s += ps[b * 128 + c];
    ss += pss[b * 128 + c];
  }
  float mu = s / (float)n;
  float var = ss / (float)n - mu * mu;
  float rs = rsqrtf(var + EPSV);
  float sc = rs * g[c];
  scale[c] = sc;
  shift[c] = fmaf(-mu, sc, be[c]);
}

// ---------------- launch ----------------

extern "C" void kernel_launch(void* const* d_in, const int* in_sizes, int n_in,
                              void* d_out, int out_size, void* d_ws, size_t ws_size,
                              hipStream_t stream) {
  const float* x   = (const float*)d_in[0];
  const int*   ei  = (const int*)d_in[1];
  const float* W1  = (const float*)d_in[2];
  const float* b1  = (const float*)d_in[3];
  const float* W2  = (const float*)d_in[4];
  const float* b2  = (const float*)d_in[5];
  const float* W3  = (const float*)d_in[6];
  const float* b3  = (const float*)d_in[7];
  const float* g1  = (const float*)d_in[8];
  const float* be1 = (const float*)d_in[9];
  const float* g2  = (const float*)d_in[10];
  const float* be2 = (const float*)d_in[11];
  float* outp = (float*)d_out;

  const int N = NNODES;
  const int E = in_sizes[1] / 2;
  const int NC = (N + 255) / 256;  // 391 (node-scan chunks)

  char* w = (char*)d_ws;
  auto alloc = [&](size_t bytes) -> void* {
    void* p = (void*)w;
    w += (bytes + 255) & ~(size_t)255;
    return p;
  };
  int*    deg    = (int*)alloc((size_t)N * 4);
  int*    rowst  = (int*)alloc((size_t)N * 4);
  int*    chunk  = (int*)alloc((size_t)(NC + 1) * 4);
  int*    csr    = (int*)alloc((size_t)E * 4);
  float*  dinv   = (float*)alloc((size_t)N * 4);
  ushort* y      = (ushort*)alloc((size_t)N * 128 * 2);  // flat bf16 y (layer3 reuses N*40)
  ushort* hpre   = (ushort*)alloc((size_t)N * 128 * 2);  // bf16 post-agg activations
  float*  ps     = (float*)alloc((size_t)256 * 128 * 4);
  float*  pss    = (float*)alloc((size_t)256 * 128 * 4);
  float*  scl    = (float*)alloc(128 * 4);
  float*  shf    = (float*)alloc(128 * 4);
  int*    hmatT  = (int*)alloc((size_t)NB * NBLK * 4);
  int*    hbaseT = (int*)alloc((size_t)NB * NBLK * 4);
  int*    btot   = (int*)alloc((size_t)NB * 4);
  int*    boff   = (int*)alloc((size_t)(NB + 1) * 4);
  ushort* Wimg1  = (ushort*)alloc((size_t)128 * 128 * 2);
  ushort* Wimg2  = (ushort*)alloc((size_t)128 * 128 * 2);
  ushort* Wimg3  = (ushort*)alloc((size_t)48 * 128 * 2);
  uint*   ebuf   = (uint*)hpre;  // alias: prep finishes before hpre is written (E*4=6.4MB <= 25.6MB)

  // W images
  wimg_all_k<<<152, 256, 0, stream>>>(W1, W2, W3, Wimg1, Wimg2, Wimg3);

  // graph prep: radix partition (no global atomics, parallel scans)
  histA_k<<<NBLK, 256, 0, stream>>>(ei, E, hmatT);
  scanM1_k<<<NB, 256, 0, stream>>>(hmatT, hbaseT, btot);
  scanM2_k<<<1, 512, 0, stream>>>(btot, boff, E);
  partB_k<<<NBLK, 256, 0, stream>>>(ei, E, hbaseT, boff, ebuf);
  histnode_k<<<NB, 256, 0, stream>>>(ebuf, boff, deg, N);
  scanA_k<<<NC, 256, 0, stream>>>(deg, rowst, chunk, N);
  scanB_k<<<1, 512, 0, stream>>>(chunk, NC);
  scanC_k<<<NC, 256, 0, stream>>>(deg, chunk, rowst, dinv, N);
  fillB_k<<<NB, 256, 0, stream>>>(ebuf, boff, rowst, csr, N, E);

  const int GB = (N + 63) / 64;  // 1563
  const int AB = (N + 3) / 4;    // 25000

  // layer 1
  gemm_mfma_k<128, false, float><<<GB, 256, 0, stream>>>(x, Wimg1, nullptr, nullptr, dinv, y, N);
  agg128_k<<<AB, 256, 0, stream>>>(y, csr, rowst, deg, dinv, b1, hpre, N);
  stats_partial_k<<<256, 256, 0, stream>>>(hpre, ps, pss, N);
  stats_final_k<<<1, 128, 0, stream>>>(ps, pss, g1, be1, scl, shf, N);
  // layer 2
  gemm_mfma_k<128, true, ushort><<<GB, 256, 0, stream>>>(hpre, Wimg2, scl, shf, dinv, y, N);
  agg128_k<<<AB, 256, 0, stream>>>(y, csr, rowst, deg, dinv, b2, hpre, N);
  stats_partial_k<<<256, 256, 0, stream>>>(hpre, ps, pss, N);
  stats_final_k<<<1, 128, 0, stream>>>(ps, pss, g2, be2, scl, shf, N);
  // layer 3 + log_softmax
  gemm_mfma_k<40, true, ushort><<<GB, 256, 0, stream>>>(hpre, Wimg3, scl, shf, dinv, y, N);
  agg40_lsm_k<<<AB, 256, 0, stream>>>(y, csr, rowst, deg, dinv, b3, outp, N);
}

// Round 13
// 495.741 us; speedup vs baseline: 1.3331x; 1.0663x over previous
//
#include <hip/hip_runtime.h>
#include <hip/hip_bf16.h>
#include <math.h>

#define NNODES 100000
#define EPSV 1e-5f
#define NB 391          // ceil(100000/256) buckets of 256 nodes
#define NBLK 256        // partition blocks (histA/partB ranges must match)
#define NSLOT 256       // stats staging slots

typedef __attribute__((ext_vector_type(8))) short short8v;   // 8 bf16 = 4 VGPR
typedef __attribute__((ext_vector_type(4))) float f32x4;

__device__ __forceinline__ ushort f2bf(float f) {
  uint u = __float_as_uint(f);
  return (ushort)((u + 0x7fffu + ((u >> 16) & 1u)) >> 16);  // RNE
}
__device__ __forceinline__ float bf2f(ushort h) { return __uint_as_float(((uint)h) << 16); }

// swizzled LDS offset for tiles with 256B rows: XOR 16B-granule index with row&7
__device__ __forceinline__ int lds_off(int row, int byteInRow) {
  return row * 256 + ((((byteInRow >> 4) ^ (row & 7)) << 4) | (byteInRow & 15));
}

// ---------------- front kernel: W images + stats-staging zero + coarse histogram ----------------
// blocks [0,152): wimg; [152,408): zero 512KB stats staging; [408,664): histA

__global__ __launch_bounds__(256) void prep0_k(const float* __restrict__ W1, const float* __restrict__ W2,
                                               const float* __restrict__ W3, ushort* __restrict__ i1,
                                               ushort* __restrict__ i2, ushort* __restrict__ i3,
                                               float* __restrict__ psAll,
                                               const int* __restrict__ ei, int E,
                                               int* __restrict__ hmatT) {
  __shared__ int lh[NB];
  int b = blockIdx.x, tid = threadIdx.x;
  if (b < 64) {
    int idx = b * 256 + tid, c = idx >> 7, k = idx & 127;
    i1[idx] = f2bf(W1[k * 128 + c]);
  } else if (b < 128) {
    int idx = (b - 64) * 256 + tid, c = idx >> 7, k = idx & 127;
    i2[idx] = f2bf(W2[k * 128 + c]);
  } else if (b < 152) {
    int idx = (b - 128) * 256 + tid, c = idx >> 7, k = idx & 127;
    i3[idx] = (c < 40) ? f2bf(W3[k * 40 + c]) : (ushort)0;
  } else if (b < 408) {
    int idx = (b - 152) * 256 + tid;           // 65536 float2 = 512KB
    *(float2*)&psAll[idx * 2] = make_float2(0.f, 0.f);
  } else {
    int hb = b - 408;                          // histA block id 0..255
    for (int i = tid; i < NB; i += 256) lh[i] = 0;
    __syncthreads();
    int per = (E + NBLK - 1) / NBLK;
    int s0 = hb * per, s1 = min(E, s0 + per);
    for (int e = s0 + tid; e < s1; e += 256)
      atomicAdd(&lh[ei[E + e] >> 8], 1);
    __syncthreads();
    for (int i = tid; i < NB; i += 256)
      hmatT[i * NBLK + hb] = lh[i];
  }
}

// ---------------- graph prep: radix partition, no global atomics ----------------

__global__ __launch_bounds__(256) void scanM1_k(const int* __restrict__ hmatT,
                                                int* __restrict__ hbaseT,
                                                int* __restrict__ btot) {
  __shared__ int sm[256];
  int i = blockIdx.x, t = threadIdx.x;
  int v = hmatT[i * NBLK + t];
  sm[t] = v;
  __syncthreads();
  for (int off = 1; off < 256; off <<= 1) {
    int u = (t >= off) ? sm[t - off] : 0;
    __syncthreads();
    sm[t] += u;
    __syncthreads();
  }
  hbaseT[i * NBLK + t] = sm[t] - v;    // exclusive within bucket
  if (t == 255) btot[i] = sm[255];
}

__global__ __launch_bounds__(512) void scanM2_k(const int* __restrict__ btot,
                                                int* __restrict__ boff, int E) {
  __shared__ int sm[512];
  int t = threadIdx.x;
  int v = (t < NB) ? btot[t] : 0;
  sm[t] = v;
  __syncthreads();
  for (int off = 1; off < 512; off <<= 1) {
    int u = (t >= off) ? sm[t - off] : 0;
    __syncthreads();
    sm[t] += u;
    __syncthreads();
  }
  if (t < NB) boff[t] = sm[t] - v;
  if (t == 0) boff[NB] = E;
}

// packed word: (dst & 255) << 17 | src   (src < 2^17)
__global__ __launch_bounds__(256) void partB_k(const int* __restrict__ ei, int E,
                                               const int* __restrict__ hbaseT,
                                               const int* __restrict__ boff,
                                               uint* __restrict__ ebuf) {
  __shared__ int cur[NB];
  for (int i = threadIdx.x; i < NB; i += 256)
    cur[i] = hbaseT[i * NBLK + blockIdx.x] + boff[i];
  __syncthreads();
  int per = (E + NBLK - 1) / NBLK;
  int s0 = blockIdx.x * per, s1 = min(E, s0 + per);
  for (int e = s0 + threadIdx.x; e < s1; e += 256) {
    int s = ei[e];
    int d = ei[E + e];
    int p = atomicAdd(&cur[d >> 8], 1);
    ebuf[p] = ((uint)(d & 255) << 17) | (uint)s;
  }
}

__global__ __launch_bounds__(256) void histnode_k(const uint* __restrict__ ebuf,
                                                  const int* __restrict__ boff,
                                                  int* __restrict__ deg, int n) {
  __shared__ int h[256];
  int b = blockIdx.x;
  h[threadIdx.x] = 0;
  __syncthreads();
  int s0 = boff[b], s1 = boff[b + 1];
  for (int i = s0 + threadIdx.x; i < s1; i += 256)
    atomicAdd(&h[ebuf[i] >> 17], 1);
  __syncthreads();
  int node = b * 256 + threadIdx.x;
  if (node < n) deg[node] = h[threadIdx.x];
}

__global__ __launch_bounds__(256) void scanA_k(const int* __restrict__ cnt, int* __restrict__ rowst,
                                               int* __restrict__ chunk, int n) {
  __shared__ int sm[256];
  int i = blockIdx.x * 256 + threadIdx.x;
  int v = (i < n) ? cnt[i] : 0;
  sm[threadIdx.x] = v;
  __syncthreads();
  for (int off = 1; off < 256; off <<= 1) {
    int t = (threadIdx.x >= off) ? sm[threadIdx.x - off] : 0;
    __syncthreads();
    sm[threadIdx.x] += t;
    __syncthreads();
  }
  if (i < n) rowst[i] = sm[threadIdx.x];
  if (threadIdx.x == 255) chunk[blockIdx.x] = sm[255];
}

__global__ __launch_bounds__(512) void scanB_k(int* __restrict__ chunk, int nc) {
  __shared__ int sm[512];
  int v = (threadIdx.x < nc) ? chunk[threadIdx.x] : 0;
  sm[threadIdx.x] = v;
  __syncthreads();
  for (int off = 1; off < 512; off <<= 1) {
    int t = (threadIdx.x >= off) ? sm[threadIdx.x - off] : 0;
    __syncthreads();
    sm[threadIdx.x] += t;
    __syncthreads();
  }
  if (threadIdx.x < nc) chunk[threadIdx.x] = sm[threadIdx.x] - v;
}

// rowst finalize + dinv fused
__global__ __launch_bounds__(256) void scanC_k(const int* __restrict__ cnt, const int* __restrict__ chunk,
                                               int* __restrict__ rowst, float* __restrict__ dinv, int n) {
  int i = blockIdx.x * 256 + threadIdx.x;
  if (i < n) {
    rowst[i] = chunk[blockIdx.x] + rowst[i] - cnt[i];
    dinv[i] = rsqrtf((float)cnt[i] + 1.0f);
  }
}

__global__ __launch_bounds__(256) void fillB_k(const uint* __restrict__ ebuf,
                                               const int* __restrict__ boff,
                                               const int* __restrict__ rowst,
                                               int* __restrict__ csr, int n, int E) {
  __shared__ int rst[256];
  __shared__ int cur[256];
  int b = blockIdx.x;
  int node = b * 256 + threadIdx.x;
  rst[threadIdx.x] = (node < n) ? rowst[node] : E;
  cur[threadIdx.x] = 0;
  __syncthreads();
  int s0 = boff[b], s1 = boff[b + 1];
  for (int i = s0 + threadIdx.x; i < s1; i += 256) {
    uint w = ebuf[i];
    int l = w >> 17;
    int p = atomicAdd(&cur[l], 1);
    csr[rst[l] + p] = (int)(w & 0x1FFFFu);
  }
}

// ---------------- MFMA GEMM: y_bf16[r][c] = dinv[r] * sum_k z[r][k] * W[k][c] ----------------
// TIN = float (layer1) or ushort/bf16 (layers 2,3). B from global bf16 W image (L2-resident).

template <int NREAL, bool BN, typename TIN>
__global__ __launch_bounds__(256) void gemm_mfma_k(const TIN* __restrict__ in, const ushort* __restrict__ Wimg,
                                                   const float* __restrict__ scale, const float* __restrict__ shift,
                                                   const float* __restrict__ dinv, ushort* __restrict__ y, int n) {
  constexpr int NT = (NREAL + 15) / 16;  // col tiles: 8 or 3
  __shared__ ushort At[64 * 128];        // swizzled A tile; reused as output tile
  const int tid = threadIdx.x;
  const int row0 = blockIdx.x * 64;

  if constexpr (sizeof(TIN) == 4) {      // fp32 input
#pragma unroll
    for (int it = 0; it < 8; ++it) {
      int f = tid + it * 256;
      int r = f >> 5, c4 = (f & 31) * 4;
      int row = row0 + r;
      float4 v;
      if (row < n) v = *(const float4*)&((const float*)in)[(size_t)row * 128 + c4];
      else v = make_float4(0.f, 0.f, 0.f, 0.f);
      if (BN) {
        float4 sc = *(const float4*)&scale[c4];
        float4 sh = *(const float4*)&shift[c4];
        v.x = fmaxf(fmaf(v.x, sc.x, sh.x), 0.f);
        v.y = fmaxf(fmaf(v.y, sc.y, sh.y), 0.f);
        v.z = fmaxf(fmaf(v.z, sc.z, sh.z), 0.f);
        v.w = fmaxf(fmaf(v.w, sc.w, sh.w), 0.f);
      }
      ushort4 h;
      h.x = f2bf(v.x); h.y = f2bf(v.y); h.z = f2bf(v.z); h.w = f2bf(v.w);
      *(ushort4*)((char*)At + lds_off(r, c4 * 2)) = h;
    }
  } else {                               // bf16 input (BN path)
    const uint* inu = (const uint*)in;   // 64 uints per row
#pragma unroll
    for (int it = 0; it < 4; ++it) {
      int f = tid + it * 256;            // 0..1023, 16B chunks
      int r = f >> 4, c8 = (f & 15) * 8;
      int row = row0 + r;
      uint4 vv;
      if (row < n) vv = *(const uint4*)&inu[(size_t)row * 64 + (c8 >> 1)];
      else vv = make_uint4(0, 0, 0, 0);
      uint outw[4];
      const uint* vp = (const uint*)&vv;
#pragma unroll
      for (int j = 0; j < 4; ++j) {
        float lo = __uint_as_float(vp[j] << 16);
        float hi = __uint_as_float(vp[j] & 0xffff0000u);
        if (BN) {
          int c = c8 + j * 2;
          lo = fmaxf(fmaf(lo, scale[c], shift[c]), 0.f);
          hi = fmaxf(fmaf(hi, scale[c + 1], shift[c + 1]), 0.f);
        }
        outw[j] = ((uint)f2bf(hi) << 16) | (uint)f2bf(lo);
      }
      *(uint4*)((char*)At + lds_off(r, c8 * 2)) = *(uint4*)outw;
    }
  }
  __syncthreads();

  const int w = tid >> 6, lane = tid & 63;
  const int lr = lane & 15, g = lane >> 4;

  short8v a[4];
#pragma unroll
  for (int kk = 0; kk < 4; ++kk)
    a[kk] = *(const short8v*)((const char*)At + lds_off(w * 16 + lr, kk * 64 + g * 16));
  float dv[4];
#pragma unroll
  for (int i = 0; i < 4; ++i) {
    int rr = row0 + w * 16 + g * 4 + i;
    dv[i] = (rr < n) ? dinv[rr] : 0.f;
  }
  __syncthreads();  // all waves done reading At -> reuse as output tile

#pragma unroll
  for (int ct = 0; ct < NT; ++ct) {
    f32x4 acc = {0.f, 0.f, 0.f, 0.f};
#pragma unroll
    for (int kk = 0; kk < 4; ++kk) {
      short8v b = *(const short8v*)&Wimg[(ct * 16 + lr) * 128 + kk * 32 + g * 8];
      acc = __builtin_amdgcn_mfma_f32_16x16x32_bf16(a[kk], b, acc, 0, 0, 0);
    }
    // C/D layout: col = lane&15, row = (lane>>4)*4 + i
#pragma unroll
    for (int i = 0; i < 4; ++i)
      *(ushort*)((char*)At + lds_off(w * 16 + g * 4 + i, (ct * 16 + lr) * 2)) = f2bf(acc[i] * dv[i]);
  }
  __syncthreads();

  if constexpr (NREAL == 128) {
#pragma unroll
    for (int it = 0; it < 4; ++it) {
      int cid = tid + it * 256;
      int r = cid >> 4, gg = cid & 15;
      int row = row0 + r;
      if (row < n) {
        short8v t = *(const short8v*)((const char*)At + lds_off(r, gg * 16));
        *(short8v*)&y[(size_t)row * 128 + gg * 8] = t;
      }
    }
  } else {
#pragma unroll
    for (int it = 0; it < 3; ++it) {
      int cid = tid + it * 256;
      if (cid < 640) {
        int r = cid / 10, u = cid - r * 10;
        int row = row0 + r;
        if (row < n) {
          ushort4 t = *(const ushort4*)((const char*)At + lds_off(r, u * 8));
          *(ushort4*)&y[(size_t)row * 40 + u * 4] = t;
        }
      }
    }
  }
}

// ---------------- aggregation (flat bf16 y, 256B gathers, 8-deep) + fused BN-stat partials ----------------
// Block = 4 waves = 4 consecutive nodes. Per-block column partials -> atomicAdd into 256-slot staging.

__global__ __launch_bounds__(256) void agg128_k(const ushort* __restrict__ y, const int* __restrict__ csr,
                                                const int* __restrict__ rowst, const int* __restrict__ deg,
                                                const float* __restrict__ dinv, const float* __restrict__ bias,
                                                ushort* __restrict__ out, float* __restrict__ ps,
                                                float* __restrict__ pss, int n) {
  __shared__ float redS[4][128], redQ[4][128];
  int wv = threadIdx.x >> 6;
  int lane = threadIdx.x & 63;
  int wid = blockIdx.x * 4 + wv;
  const uint* yu = (const uint*)y;      // 64 uints (128 bf16) per row
  float ox = 0.f, oy = 0.f;
  if (wid < n) {
    int base = rowst[wid];
    int dg = deg[wid];
    float p0[8], p1[8];
#pragma unroll
    for (int j = 0; j < 8; ++j) { p0[j] = 0.f; p1[j] = 0.f; }
    int t = 0;
    for (; t + 8 <= dg; t += 8) {
      int sidx[8];
#pragma unroll
      for (int j = 0; j < 8; ++j) sidx[j] = csr[base + t + j];
      uint v[8];
#pragma unroll
      for (int j = 0; j < 8; ++j) v[j] = yu[(size_t)sidx[j] * 64 + lane];
#pragma unroll
      for (int j = 0; j < 8; ++j) {
        p0[j] += __uint_as_float(v[j] << 16);
        p1[j] += __uint_as_float(v[j] & 0xffff0000u);
      }
    }
    for (; t < dg; ++t) {
      int s = csr[base + t];
      uint v = yu[(size_t)s * 64 + lane];
      p0[0] += __uint_as_float(v << 16);
      p1[0] += __uint_as_float(v & 0xffff0000u);
    }
    uint vs = yu[(size_t)wid * 64 + lane];
    p0[0] += __uint_as_float(vs << 16);
    p1[0] += __uint_as_float(vs & 0xffff0000u);
    float s0 = ((p0[0] + p0[1]) + (p0[2] + p0[3])) + ((p0[4] + p0[5]) + (p0[6] + p0[7]));
    float s1 = ((p1[0] + p1[1]) + (p1[2] + p1[3])) + ((p1[4] + p1[5]) + (p1[6] + p1[7]));
    float dvv = dinv[wid];
    float2 bb = *(const float2*)&bias[lane * 2];
    ox = fmaf(s0, dvv, bb.x);
    oy = fmaf(s1, dvv, bb.y);
    ((uint*)out)[(size_t)wid * 64 + lane] = ((uint)f2bf(oy) << 16) | (uint)f2bf(ox);
  }
  // fused stats partials (bf16-rounded values, matching what downstream reads)
  float rx = (wid < n) ? bf2f(f2bf(ox)) : 0.f;
  float ry = (wid < n) ? bf2f(f2bf(oy)) : 0.f;
  redS[wv][lane * 2] = rx;
  redS[wv][lane * 2 + 1] = ry;
  redQ[wv][lane * 2] = rx * rx;
  redQ[wv][lane * 2 + 1] = ry * ry;
  __syncthreads();
  if (threadIdx.x < 128) {
    int c = threadIdx.x;
    float s = (redS[0][c] + redS[1][c]) + (redS[2][c] + redS[3][c]);
    float q = (redQ[0][c] + redQ[1][c]) + (redQ[2][c] + redQ[3][c]);
    int slot = blockIdx.x & (NSLOT - 1);
    atomicAdd(&ps[slot * 128 + c], s);
    atomicAdd(&pss[slot * 128 + c], q);
  }
}

// ---------------- last layer: aggregation (d=40) + bias + log_softmax ----------------

__global__ __launch_bounds__(256) void agg40_lsm_k(const ushort* __restrict__ y, const int* __restrict__ csr,
                                                   const int* __restrict__ rowst, const int* __restrict__ deg,
                                                   const float* __restrict__ dinv, const float* __restrict__ bias,
                                                   float* __restrict__ out, int n) {
  int wid = (blockIdx.x * 256 + threadIdx.x) >> 6;
  if (wid >= n) return;
  int lane = threadIdx.x & 63;
  int col = lane < 40 ? lane : 39;
  int base = rowst[wid];
  int dg = deg[wid];
  float a = 0.f, b = 0.f, c = 0.f, d = 0.f;
  int t = 0;
  for (; t + 4 <= dg; t += 4) {
    int s0 = csr[base + t], s1 = csr[base + t + 1], s2 = csr[base + t + 2], s3 = csr[base + t + 3];
    a += bf2f(y[(size_t)s0 * 40 + col]);
    b += bf2f(y[(size_t)s1 * 40 + col]);
    c += bf2f(y[(size_t)s2 * 40 + col]);
    d += bf2f(y[(size_t)s3 * 40 + col]);
  }
  for (; t < dg; ++t) {
    int s = csr[base + t];
    a += bf2f(y[(size_t)s * 40 + col]);
  }
  a += bf2f(y[(size_t)wid * 40 + col]);
  float v = fmaf((a + b) + (c + d), dinv[wid], bias[col]);
  bool act = lane < 40;
  float m = act ? v : -INFINITY;
#pragma unroll
  for (int off = 32; off; off >>= 1) m = fmaxf(m, __shfl_xor(m, off));
  float e = act ? expf(v - m) : 0.f;
  float se = e;
#pragma unroll
  for (int off = 32; off; off >>= 1) se += __shfl_xor(se, off);
  if (act) out[(size_t)wid * 40 + lane] = v - m - logf(se);
}

// ---------------- BN stats final (reads 256-slot staging) ----------------

__global__ __launch_bounds__(128) void stats_final_k(const float* __restrict__ ps, const float* __restrict__ pss,
                                                     const float* __restrict__ g, const float* __restrict__ be,
                                                     float* __restrict__ scale, float* __restrict__ shift, int n) {
  int c = threadIdx.x;
  float s = 0.f, ss = 0.f;
  for (int b = 0; b < NSLOT; ++b) {
    s += ps[b * 128 + c];
    ss += pss[b * 128 + c];
  }
  float mu = s / (float)n;
  float var = ss / (float)n - mu * mu;
  float rs = rsqrtf(var + EPSV);
  float sc = rs * g[c];
  scale[c] = sc;
  shift[c] = fmaf(-mu, sc, be[c]);
}

// ---------------- launch ----------------

extern "C" void kernel_launch(void* const* d_in, const int* in_sizes, int n_in,
                              void* d_out, int out_size, void* d_ws, size_t ws_size,
                              hipStream_t stream) {
  const float* x   = (const float*)d_in[0];
  const int*   ei  = (const int*)d_in[1];
  const float* W1  = (const float*)d_in[2];
  const float* b1  = (const float*)d_in[3];
  const float* W2  = (const float*)d_in[4];
  const float* b2  = (const float*)d_in[5];
  const float* W3  = (const float*)d_in[6];
  const float* b3  = (const float*)d_in[7];
  const float* g1  = (const float*)d_in[8];
  const float* be1 = (const float*)d_in[9];
  const float* g2  = (const float*)d_in[10];
  const float* be2 = (const float*)d_in[11];
  float* outp = (float*)d_out;

  const int N = NNODES;
  const int E = in_sizes[1] / 2;
  const int NC = (N + 255) / 256;  // 391 (node-scan chunks)

  char* w = (char*)d_ws;
  auto alloc = [&](size_t bytes) -> void* {
    void* p = (void*)w;
    w += (bytes + 255) & ~(size_t)255;
    return p;
  };
  int*    deg    = (int*)alloc((size_t)N * 4);
  int*    rowst  = (int*)alloc((size_t)N * 4);
  int*    chunk  = (int*)alloc((size_t)(NC + 1) * 4);
  int*    csr    = (int*)alloc((size_t)E * 4);
  float*  dinv   = (float*)alloc((size_t)N * 4);
  ushort* y      = (ushort*)alloc((size_t)N * 128 * 2);  // flat bf16 y (layer3 reuses N*40)
  ushort* hpre   = (ushort*)alloc((size_t)N * 128 * 2);  // bf16 post-agg activations
  float*  psAll  = (float*)alloc((size_t)4 * NSLOT * 128 * 4);  // psA,pssA,psB,pssB (zeroed in prep0)
  float*  psA    = psAll;
  float*  pssA   = psAll + NSLOT * 128;
  float*  psB    = psAll + 2 * NSLOT * 128;
  float*  pssB   = psAll + 3 * NSLOT * 128;
  float*  scl    = (float*)alloc(128 * 4);
  float*  shf    = (float*)alloc(128 * 4);
  int*    hmatT  = (int*)alloc((size_t)NB * NBLK * 4);
  int*    hbaseT = (int*)alloc((size_t)NB * NBLK * 4);
  int*    btot   = (int*)alloc((size_t)NB * 4);
  int*    boff   = (int*)alloc((size_t)(NB + 1) * 4);
  ushort* Wimg1  = (ushort*)alloc((size_t)128 * 128 * 2);
  ushort* Wimg2  = (ushort*)alloc((size_t)128 * 128 * 2);
  ushort* Wimg3  = (ushort*)alloc((size_t)48 * 128 * 2);
  uint*   ebuf   = (uint*)hpre;  // alias: prep finishes before hpre is written (E*4=6.4MB <= 25.6MB)

  // front kernel: W images + stats-zero + coarse histogram
  prep0_k<<<664, 256, 0, stream>>>(W1, W2, W3, Wimg1, Wimg2, Wimg3, psAll, ei, E, hmatT);

  // graph prep: radix partition (no global atomics, parallel scans)
  scanM1_k<<<NB, 256, 0, stream>>>(hmatT, hbaseT, btot);
  scanM2_k<<<1, 512, 0, stream>>>(btot, boff, E);
  partB_k<<<NBLK, 256, 0, stream>>>(ei, E, hbaseT, boff, ebuf);
  histnode_k<<<NB, 256, 0, stream>>>(ebuf, boff, deg, N);
  scanA_k<<<NC, 256, 0, stream>>>(deg, rowst, chunk, N);
  scanB_k<<<1, 512, 0, stream>>>(chunk, NC);
  scanC_k<<<NC, 256, 0, stream>>>(deg, chunk, rowst, dinv, N);
  fillB_k<<<NB, 256, 0, stream>>>(ebuf, boff, rowst, csr, N, E);

  const int GB = (N + 63) / 64;  // 1563
  const int AB = (N + 3) / 4;    // 25000

  // layer 1
  gemm_mfma_k<128, false, float><<<GB, 256, 0, stream>>>(x, Wimg1, nullptr, nullptr, dinv, y, N);
  agg128_k<<<AB, 256, 0, stream>>>(y, csr, rowst, deg, dinv, b1, hpre, psA, pssA, N);
  stats_final_k<<<1, 128, 0, stream>>>(psA, pssA, g1, be1, scl, shf, N);
  // layer 2
  gemm_mfma_k<128, true, ushort><<<GB, 256, 0, stream>>>(hpre, Wimg2, scl, shf, dinv, y, N);
  agg128_k<<<AB, 256, 0, stream>>>(y, csr, rowst, deg, dinv, b2, hpre, psB, pssB, N);
  stats_final_k<<<1, 128, 0, stream>>>(psB, pssB, g2, be2, scl, shf, N);
  // layer 3 + log_softmax
  gemm_mfma_k<40, true, ushort><<<GB, 256, 0, stream>>>(hpre, Wimg3, scl, shf, dinv, y, N);
  agg40_lsm_k<<<AB, 256, 0, stream>>>(y, csr, rowst, deg, dinv, b3, outp, N);
}